// Round 1
// 822.807 us; speedup vs baseline: 1.1225x; 1.1225x over previous
//
#include <hip/hip_runtime.h>

#define N_NODES 100000
#define N_EDGES 1600000
#define D_IN    256
#define D_HID   64
#define D_OUT   40
#define PROP_N  16

typedef short short8 __attribute__((ext_vector_type(8)));   // 8 bf16 (4 VGPRs)
typedef float f32x4  __attribute__((ext_vector_type(4)));   // MFMA accumulator

// ---- fp8 (OCP e4m3) helpers: HW convert, RNE, saturating ------------------
__device__ __forceinline__ unsigned char f32_to_fp8(float f) {
    int p = __builtin_amdgcn_cvt_pk_fp8_f32(f, f, 0, false);
    return (unsigned char)(p & 0xff);
}
// ---- bf16 helpers (RNE) ---------------------------------------------------
__device__ __forceinline__ unsigned short f32_to_bf16(float f) {
    unsigned int u = __float_as_uint(f);
    unsigned int r = (u + 0x7fffu + ((u >> 16) & 1u)) >> 16;
    return (unsigned short)r;
}
__device__ __forceinline__ unsigned int f32x2_to_bf16x2(float lo, float hi) {
    return (unsigned int)f32_to_bf16(lo) | ((unsigned int)f32_to_bf16(hi) << 16);
}
// decode packed edge: bits[31:15]=col, bits[14:0]=bf16(val) without sign
__device__ __forceinline__ float edge_val(unsigned p) {
    return __uint_as_float((p & 0x7fffu) << 16);
}
// 4-feature fp8 FMA: b holds 4 fp8 bytes (features f..f+3, little-endian)
__device__ __forceinline__ void fma4(float4& a, float v, unsigned b) {
    a.x = fmaf(v, __builtin_amdgcn_cvt_f32_fp8((int)b, 0), a.x);
    a.y = fmaf(v, __builtin_amdgcn_cvt_f32_fp8((int)b, 1), a.y);
    a.z = fmaf(v, __builtin_amdgcn_cvt_f32_fp8((int)b, 2), a.z);
    a.w = fmaf(v, __builtin_amdgcn_cvt_f32_fp8((int)b, 3), a.w);
}

// ---------------------------------------------------------------------------
// Kernel 1: CSR row_ptr from sorted edge_row via binary search.
// ---------------------------------------------------------------------------
__global__ __launch_bounds__(256) void build_rowptr(const int* __restrict__ erow,
                                                    int* __restrict__ rp) {
    int r = blockIdx.x * blockDim.x + threadIdx.x;
    if (r > N_NODES) return;
    int lo = 0, hi = N_EDGES;
    while (lo < hi) {
        int mid = (lo + hi) >> 1;
        if (erow[mid] < r) lo = mid + 1; else hi = mid;
    }
    rp[r] = lo;
}

// ---------------------------------------------------------------------------
// Kernel 1b: pack (col, val) into ONE dword -> 4 B/edge streamed per step.
//   bits[31:15] = col (100000 < 2^17), bits[14:0] = bf16(val) sans sign
//   (val >= 0 always). bf16 rel err 2^-9 << fp8 gather err already present.
// ---------------------------------------------------------------------------
__global__ __launch_bounds__(256) void pack_edges4(const int* __restrict__ ecol,
                                                   const float* __restrict__ evalv,
                                                   unsigned* __restrict__ ep4) {
    int i = blockIdx.x * blockDim.x + threadIdx.x;
    if (i >= N_EDGES) return;
    unsigned bf = f32_to_bf16(evalv[i]);
    ep4[i] = ((unsigned)ecol[i] << 15) | (bf & 0x7fffu);
}

// ---------------------------------------------------------------------------
// Kernel 1c: W1 [256][64] fp32 -> W1T [64][256] bf16 (for MFMA B-fragments).
// ---------------------------------------------------------------------------
__global__ __launch_bounds__(256) void prep_w1t(const float* __restrict__ W1,
                                                unsigned short* __restrict__ W1T) {
    int i = blockIdx.x * 256 + threadIdx.x;           // 16384 elements
    if (i >= D_IN * D_HID) return;
    int k = i >> 6, n = i & 63;
    W1T[n * 256 + k] = f32_to_bf16(W1[i]);
}

// ---------------------------------------------------------------------------
// Kernel 2 (MFMA): h = x @ W1 + b1 ; Y0f = h ; Y08 = fp8(h) ; src = 0.5*diag*h
// CHANGE vs prev: preload the full 16-row x tile (16 float4/lane) into
// registers BEFORE the pack/MFMA chain. Prev version had 28 VGPRs => ~2
// loads in flight => latency-serialized (22% HBM, 6% VALU). launch_bounds
// (64,4) caps at 128 VGPRs so all 16 HBM loads stay outstanding.
// ---------------------------------------------------------------------------
__global__ __launch_bounds__(64, 4) void mlp1(const float* __restrict__ x,
                                              const unsigned short* __restrict__ W1T,
                                              const float* __restrict__ b1,
                                              const float* __restrict__ diag,
                                              float* __restrict__ Y0f,
                                              unsigned char* __restrict__ Y08,
                                              float* __restrict__ src) {
    const int lane  = threadIdx.x;
    const int l15   = lane & 15;
    const int quad  = lane >> 4;
    const int mbase = blockIdx.x * 16;      // 6250 * 16 == 100000 exactly

    const float* xrow = x + (size_t)(mbase + l15) * D_IN + quad * 8;
    float4 xr[16];
    #pragma unroll
    for (int i = 0; i < 8; ++i) {
        xr[2 * i]     = *(const float4*)(xrow + i * 32);
        xr[2 * i + 1] = *(const float4*)(xrow + i * 32 + 4);
    }

    f32x4 acc[4] = {};
    #pragma unroll
    for (int ks = 0; ks < 8; ++ks) {
        union { short8 v; unsigned int u[4]; } a;
        a.u[0] = f32x2_to_bf16x2(xr[2 * ks].x, xr[2 * ks].y);
        a.u[1] = f32x2_to_bf16x2(xr[2 * ks].z, xr[2 * ks].w);
        a.u[2] = f32x2_to_bf16x2(xr[2 * ks + 1].x, xr[2 * ks + 1].y);
        a.u[3] = f32x2_to_bf16x2(xr[2 * ks + 1].z, xr[2 * ks + 1].w);

        #pragma unroll
        for (int ct = 0; ct < 4; ++ct) {
            short8 b = *(const short8*)(W1T + (ct * 16 + l15) * 256 + ks * 32 + quad * 8);
            acc[ct] = __builtin_amdgcn_mfma_f32_16x16x32_bf16(a.v, b, acc[ct], 0, 0, 0);
        }
    }

    float bias[4];
    #pragma unroll
    for (int ct = 0; ct < 4; ++ct) bias[ct] = b1[ct * 16 + l15];

    #pragma unroll
    for (int reg = 0; reg < 4; ++reg) {
        const int mr = mbase + quad * 4 + reg;
        const float dg = diag[mr];
        #pragma unroll
        for (int ct = 0; ct < 4; ++ct) {
            const int col = ct * 16 + l15;
            const float h = acc[ct][reg] + bias[ct];
            const size_t idx = (size_t)mr * 64 + col;
            Y0f[idx] = h;
            src[idx] = 0.5f * dg * h;
            Y08[idx] = f32_to_fp8(h);
        }
    }
}

// ---------------------------------------------------------------------------
// Kernel 3: one propagation step — RESTRUCTURED.
// 4 rows per wave, 16 lanes per row; each lane owns 4 features (one dword of
// the fp8 row). One gather instruction now covers 4 edges (4 cache lines),
// 4-deep unroll per row-group => 16 lines in flight per wave, 4x fewer
// gather VMEM instructions (0.4M vs 1.6M per step), 4x fewer waves, and
// features stay lane-local (no cross-lane reduction). Edge record is 4 B.
// ---------------------------------------------------------------------------
__global__ __launch_bounds__(256) void prop_step(const float* __restrict__ Yf,
                                                 const unsigned char* __restrict__ Y8,
                                                 const float* __restrict__ src,
                                                 float* __restrict__ Yof,
                                                 unsigned char* __restrict__ Yo8,
                                                 const int* __restrict__ rp,
                                                 const unsigned* __restrict__ ep4) {
    const int wid  = blockIdx.x * 4 + (threadIdx.x >> 6);   // 25000 waves
    const int lane = threadIdx.x & 63;
    const int g    = lane >> 4;         // row group 0..3
    const int fl   = lane & 15;         // feature-quad index (features 4*fl..4*fl+3)
    const int row  = wid * 4 + g;
    if (row >= N_NODES) return;         // exact: 100000 = 4 * 25000

    const int e0 = rp[row];
    const int e1 = rp[row + 1];

    const size_t fb = (size_t)row * 64 + fl * 4;
    const float4 yself = *(const float4*)(Yf + fb);
    const float4 sv    = *(const float4*)(src + fb);
    const unsigned char* Y8f = Y8 + fl * 4;

    float4 acc0 = make_float4(0.f, 0.f, 0.f, 0.f);
    float4 acc1 = acc0, acc2 = acc0, acc3 = acc0;

    int e = e0;
    for (; e + 4 <= e1; e += 4) {
        unsigned p0 = ep4[e + 0], p1 = ep4[e + 1], p2 = ep4[e + 2], p3 = ep4[e + 3];
        unsigned b0 = *(const unsigned*)(Y8f + ((size_t)(p0 >> 15) << 6));
        unsigned b1 = *(const unsigned*)(Y8f + ((size_t)(p1 >> 15) << 6));
        unsigned b2 = *(const unsigned*)(Y8f + ((size_t)(p2 >> 15) << 6));
        unsigned b3 = *(const unsigned*)(Y8f + ((size_t)(p3 >> 15) << 6));
        fma4(acc0, edge_val(p0), b0);
        fma4(acc1, edge_val(p1), b1);
        fma4(acc2, edge_val(p2), b2);
        fma4(acc3, edge_val(p3), b3);
    }
    for (; e < e1; ++e) {
        unsigned p = ep4[e];
        unsigned b = *(const unsigned*)(Y8f + ((size_t)(p >> 15) << 6));
        fma4(acc0, edge_val(p), b);
    }

    float4 accs;
    accs.x = (acc0.x + acc1.x) + (acc2.x + acc3.x);
    accs.y = (acc0.y + acc1.y) + (acc2.y + acc3.y);
    accs.z = (acc0.z + acc1.z) + (acc2.z + acc3.z);
    accs.w = (acc0.w + acc1.w) + (acc2.w + acc3.w);

    float4 o;
    o.x = fmaf(0.5f, yself.x, fmaf(0.5f, accs.x, sv.x));
    o.y = fmaf(0.5f, yself.y, fmaf(0.5f, accs.y, sv.y));
    o.z = fmaf(0.5f, yself.z, fmaf(0.5f, accs.z, sv.z));
    o.w = fmaf(0.5f, yself.w, fmaf(0.5f, accs.w, sv.w));

    *(float4*)(Yof + fb) = o;
    int pk = __builtin_amdgcn_cvt_pk_fp8_f32(o.x, o.y, 0, false);   // bytes 0,1
    pk     = __builtin_amdgcn_cvt_pk_fp8_f32(o.z, o.w, pk, true);   // bytes 2,3
    *(unsigned*)(Yo8 + fb) = (unsigned)pk;
}

// ---------------------------------------------------------------------------
// Kernel 4: out = relu(Y) @ W2 + b2.  One node per thread, 40 accumulators.
// ---------------------------------------------------------------------------
__global__ __launch_bounds__(256) void mlp2(const float* __restrict__ Y,
                                            const float* __restrict__ W2,
                                            const float* __restrict__ b2,
                                            float* __restrict__ out) {
    __shared__ float W2s[D_HID * D_OUT];
    __shared__ float b2s[D_OUT];
    int tid = threadIdx.x;
    for (int i = tid; i < D_HID * D_OUT; i += 256) W2s[i] = W2[i];
    if (tid < D_OUT) b2s[tid] = b2[tid];
    __syncthreads();

    int n = blockIdx.x * 256 + tid;
    if (n >= N_NODES) return;

    float acc[D_OUT];
    #pragma unroll
    for (int o = 0; o < D_OUT; ++o) acc[o] = b2s[o];

    const float4* Y4 = (const float4*)(Y + (size_t)n * 64);
    #pragma unroll 4
    for (int k4 = 0; k4 < 16; ++k4) {
        float4 y = Y4[k4];
        float ys[4];
        ys[0] = fmaxf(y.x, 0.0f); ys[1] = fmaxf(y.y, 0.0f);
        ys[2] = fmaxf(y.z, 0.0f); ys[3] = fmaxf(y.w, 0.0f);
        #pragma unroll
        for (int j = 0; j < 4; ++j) {
            int k = k4 * 4 + j;
            #pragma unroll
            for (int o = 0; o < D_OUT; ++o)
                acc[o] = fmaf(ys[j], W2s[k * D_OUT + o], acc[o]);
        }
    }

    float4* o4 = (float4*)(out + (size_t)n * D_OUT);
    #pragma unroll
    for (int q = 0; q < 10; ++q)
        o4[q] = make_float4(acc[4 * q], acc[4 * q + 1], acc[4 * q + 2], acc[4 * q + 3]);
}

// ---------------------------------------------------------------------------
extern "C" void kernel_launch(void* const* d_in, const int* in_sizes, int n_in,
                              void* d_out, int out_size, void* d_ws, size_t ws_size,
                              hipStream_t stream) {
    const float* x     = (const float*)d_in[0];
    const int*   erow  = (const int*)  d_in[1];
    const int*   ecol  = (const int*)  d_in[2];
    const float* evalv = (const float*)d_in[3];
    const float* diag  = (const float*)d_in[4];
    const float* W1    = (const float*)d_in[5];
    const float* b1    = (const float*)d_in[6];
    const float* W2    = (const float*)d_in[7];
    const float* b2    = (const float*)d_in[8];
    float* out = (float*)d_out;

    // workspace: Y0f|Y1f|src (fp32) | Y08|Y18 (fp8) | ep4 (4B/edge) | rp | W1T
    const size_t NV = (size_t)N_NODES * D_HID;
    float*          Y0f = (float*)d_ws;
    float*          Y1f = Y0f + NV;
    float*          src = Y1f + NV;
    unsigned char*  Y08 = (unsigned char*)(src + NV);
    unsigned char*  Y18 = Y08 + NV;
    unsigned*       ep4 = (unsigned*)(Y18 + NV);
    int*            rp  = (int*)(ep4 + N_EDGES);
    unsigned short* W1T = (unsigned short*)
        (((unsigned long long)(rp + N_NODES + 1) + 15ull) & ~15ull);

    build_rowptr<<<(N_NODES + 1 + 255) / 256, 256, 0, stream>>>(erow, rp);
    pack_edges4<<<(N_EDGES + 255) / 256, 256, 0, stream>>>(ecol, evalv, ep4);
    prep_w1t<<<(D_IN * D_HID + 255) / 256, 256, 0, stream>>>(W1, W1T);
    mlp1<<<N_NODES / 16, 64, 0, stream>>>(x, W1T, b1, diag, Y0f, Y08, src);

    float*         Yf[2] = {Y0f, Y1f};
    unsigned char* Y8[2] = {Y08, Y18};
    for (int i = 0; i < PROP_N; ++i) {
        prop_step<<<N_NODES / 16, 256, 0, stream>>>(
            Yf[i & 1], Y8[i & 1], src, Yf[(i + 1) & 1], Y8[(i + 1) & 1], rp, ep4);
    }
    // PROP_N even -> final fp32 result in Y0f
    mlp2<<<(N_NODES + 255) / 256, 256, 0, stream>>>(Y0f, W2, b2, out);
}